// Round 11
// baseline (399.921 us; speedup 1.0000x reference)
//
#include <hip/hip_runtime.h>

#define HID 40
#define RBKT 196          // buckets of 512 nodes: covers n <= 100352
#define BSH 9             // bucket shift (512 nodes per bucket)
#define CAP 12288         // per-bucket edge capacity (mean 8192, +45 sigma)
#define EPB 4096          // edges per block in binning pass

// ---------------- bf16 helpers ----------------

__device__ inline unsigned pack2_bf16(float a, float b) {
    unsigned ua = __float_as_uint(a);
    unsigned ub = __float_as_uint(b);
    ua = (ua + 0x7fffu + ((ua >> 16) & 1u)) >> 16;            // RNE, low half
    ub = (ub + 0x7fffu + ((ub >> 16) & 1u)) & 0xffff0000u;    // RNE, high half
    return ua | ub;
}

__device__ inline void acc8_bf16(float* acc, uint4 v) {
    acc[0] += __uint_as_float(v.x << 16);
    acc[1] += __uint_as_float(v.x & 0xffff0000u);
    acc[2] += __uint_as_float(v.y << 16);
    acc[3] += __uint_as_float(v.y & 0xffff0000u);
    acc[4] += __uint_as_float(v.z << 16);
    acc[5] += __uint_as_float(v.z & 0xffff0000u);
    acc[6] += __uint_as_float(v.w << 16);
    acc[7] += __uint_as_float(v.w & 0xffff0000u);
}

__global__ void clear_kernel(int* __restrict__ bucket_cnt, float* __restrict__ g_sum, int G) {
    int t = blockIdx.x * blockDim.x + threadIdx.x;
    if (t < RBKT) bucket_cnt[t] = 0;
    if (t < G) g_sum[t] = 0.f;
}

// ---------------- CSR build (two-level bucketed) ----------------

__global__ __launch_bounds__(256) void binA_kernel(
        const int* __restrict__ esrc, const int* __restrict__ edst, int E,
        int* __restrict__ bucket_cnt, int* __restrict__ bucket_data) {
    __shared__ int cnt_l[RBKT];
    __shared__ int base_l[RBKT];
    int t = threadIdx.x;
    for (int b = t; b < RBKT; b += 256) cnt_l[b] = 0;
    __syncthreads();
    int e0 = blockIdx.x * EPB;
    int e1 = min(e0 + EPB, E);
    for (int e = e0 + t; e < e1; e += 256) {
        atomicAdd(&cnt_l[edst[e] >> BSH], 1);
    }
    __syncthreads();
    for (int b = t; b < RBKT; b += 256) {
        int c = cnt_l[b];
        base_l[b] = (c > 0) ? atomicAdd(&bucket_cnt[b], c) : 0;
        cnt_l[b] = 0;
    }
    __syncthreads();
    for (int e = e0 + t; e < e1; e += 256) {
        int d = edst[e];
        int s = esrc[e];
        int b = d >> BSH;
        int off = base_l[b] + atomicAdd(&cnt_l[b], 1);
        if (off < CAP) bucket_data[(size_t)b * CAP + off] = (s << BSH) | (d & 511);
    }
}

__global__ void scan_buckets_kernel(const int* __restrict__ cnt, int* __restrict__ base) {
    __shared__ int s[256];
    int t = threadIdx.x;
    int c = (t < RBKT) ? min(cnt[t], CAP) : 0;
    s[t] = c;
    __syncthreads();
    for (int off = 1; off < 256; off <<= 1) {
        int y = (t >= off) ? s[t - off] : 0;
        __syncthreads();
        s[t] += y;
        __syncthreads();
    }
    if (t < RBKT) base[t] = s[t] - c;
    if (t == RBKT - 1) base[RBKT] = s[t];
}

__global__ __launch_bounds__(256) void buildB_kernel(
        const int* __restrict__ bucket_cnt, const int* __restrict__ bucket_base,
        const int* __restrict__ bucket_data,
        int* __restrict__ rowptr, int* __restrict__ csr,
        float* __restrict__ dinv, int n) {
    __shared__ int deg_l[512];
    __shared__ int off_l[512];
    __shared__ int ps[256];
    int r = blockIdx.x;
    int t = threadIdx.x;
    int cnt = min(bucket_cnt[r], CAP);
    int base = bucket_base[r];
    int node0 = r << BSH;
    int nr = min(512, n - node0);
    for (int i = t; i < 512; i += 256) deg_l[i] = 0;
    __syncthreads();
    const int* data = bucket_data + (size_t)r * CAP;
    for (int e = t; e < cnt; e += 256) atomicAdd(&deg_l[data[e] & 511], 1);
    __syncthreads();
    int a0 = deg_l[2 * t], a1 = deg_l[2 * t + 1];
    ps[t] = a0 + a1;
    __syncthreads();
    for (int off = 1; off < 256; off <<= 1) {
        int y = (t >= off) ? ps[t - off] : 0;
        __syncthreads();
        ps[t] += y;
        __syncthreads();
    }
    int excl = ps[t] - (a0 + a1);
    off_l[2 * t] = excl;
    off_l[2 * t + 1] = excl + a0;
    __syncthreads();
    for (int i = t; i < nr; i += 256) {
        rowptr[node0 + i] = base + off_l[i];
        dinv[node0 + i] = rsqrtf((float)(deg_l[i] + 1));
    }
    if (r == RBKT - 1 && t == 0) rowptr[n] = base + cnt;
    __syncthreads();
    for (int e = t; e < cnt; e += 256) {
        int v = data[e];
        int p = atomicAdd(&off_l[v & 511], 1);
        csr[base + p] = v >> BSH;
    }
}

// ---------------- layer kernels ----------------

// x (f32, n x 30) * dinv -> bf16 table, 16 uints/row (32 slots, last 2 zero)
__global__ __launch_bounds__(256) void scale_bf16_kernel(
        const float* __restrict__ x, const float* __restrict__ dinv,
        unsigned* __restrict__ xs, int n) {
    int t = blockIdx.x * blockDim.x + threadIdx.x;
    int i = t >> 4, p = t & 15;
    if (i >= n) return;
    float a = 0.f, b = 0.f;
    if (p < 15) {
        float d = dinv[i];
        a = x[i * 30 + 2 * p] * d;
        b = x[i * 30 + 2 * p + 1] * d;
    }
    xs[(size_t)i * 16 + p] = pack2_bf16(a, b);
}

// Fused gather + transform (+ optional pool) — round-7 structure (unroll 4).
// SPLIT_IN=false: input rows = TPN uint4s (layer 1: 64 B rows).
// SPLIT_IN=true : input = lo table (4 uint4s = 64 B, line-aligned, feats 0-31)
//                 + hi table (1 uint4 = 16 B, feats 32-39, 1.6 MB, L2-resident).
//                 Slices q<4 read lo[s*4+q]; slice q==TPN-1 reads hi[s].
//                 Both strides are compile-time (no runtime mul -> no spills).
// Output (!POOL): split lo/hi tables, 20 uints/row total.
template <int INF, int TPN, bool SPLIT_IN, bool POOL>
__global__ __launch_bounds__(64 * TPN) void fused_layer_kernel(
        const unsigned* __restrict__ xs_lo, const unsigned* __restrict__ xs_hi,
        const int* __restrict__ rowptr, const int* __restrict__ csr,
        const float* __restrict__ dinv,
        const float* __restrict__ W, const float* __restrict__ bias,
        const float* __restrict__ lin_w, const int* __restrict__ batch,
        unsigned* __restrict__ go_lo, unsigned* __restrict__ go_hi,
        float* __restrict__ g_sum, int n) {
    constexpr int NT   = 64 * TPN;      // block threads
    constexpr int STR  = 8 * TPN + 1;   // agg LDS row stride (floats)
    constexpr int OUTF = 40;
    constexpr int OPF  = OUTF / TPN;    // outputs per thread
    __shared__ float Ws[INF * OUTF];
    __shared__ float aggs[64 * STR];
    __shared__ float lw[POOL ? OUTF : 1];
    __shared__ float sarr[POOL ? NT : 1];
    const int tid = threadIdx.x;
    for (int t = tid; t < INF * OUTF; t += NT) Ws[t] = W[t];
    if (POOL) {
        for (int t = tid; t < OUTF; t += NT) lw[t] = lin_w[t];
    }
    const int node_l = tid / TPN, q = tid - node_l * TPN;
    const int node = blockIdx.x * 64 + node_l;
    const bool valid = (node < n);
    if (valid) {
        float acc[8];
        int e0 = rowptr[node], e1 = rowptr[node + 1];
        if (!SPLIT_IN || q != TPN - 1) {
            // lo path: 64 B rows, compile-time stride 4 uint4s
            constexpr int MUL = SPLIT_IN ? 4 : TPN;
            const uint4* tab = reinterpret_cast<const uint4*>(xs_lo) + q;
            {
                uint4 v = tab[(size_t)node * MUL];     // self loop
                acc[0] = __uint_as_float(v.x << 16);
                acc[1] = __uint_as_float(v.x & 0xffff0000u);
                acc[2] = __uint_as_float(v.y << 16);
                acc[3] = __uint_as_float(v.y & 0xffff0000u);
                acc[4] = __uint_as_float(v.z << 16);
                acc[5] = __uint_as_float(v.z & 0xffff0000u);
                acc[6] = __uint_as_float(v.w << 16);
                acc[7] = __uint_as_float(v.w & 0xffff0000u);
            }
            int e = e0;
            for (; e + 4 <= e1; e += 4) {              // 4-way unroll
                int s0 = csr[e], s1 = csr[e + 1], s2 = csr[e + 2], s3 = csr[e + 3];
                uint4 v0 = tab[(size_t)s0 * MUL];
                uint4 v1 = tab[(size_t)s1 * MUL];
                uint4 v2 = tab[(size_t)s2 * MUL];
                uint4 v3 = tab[(size_t)s3 * MUL];
                acc8_bf16(acc, v0);
                acc8_bf16(acc, v1);
                acc8_bf16(acc, v2);
                acc8_bf16(acc, v3);
            }
            for (; e < e1; e++) {
                acc8_bf16(acc, tab[(size_t)csr[e] * MUL]);
            }
        } else {
            // hi path: 16 B rows, table L2-resident
            const uint4* tabh = reinterpret_cast<const uint4*>(xs_hi);
            {
                uint4 v = tabh[node];                  // self loop
                acc[0] = __uint_as_float(v.x << 16);
                acc[1] = __uint_as_float(v.x & 0xffff0000u);
                acc[2] = __uint_as_float(v.y << 16);
                acc[3] = __uint_as_float(v.y & 0xffff0000u);
                acc[4] = __uint_as_float(v.z << 16);
                acc[5] = __uint_as_float(v.z & 0xffff0000u);
                acc[6] = __uint_as_float(v.w << 16);
                acc[7] = __uint_as_float(v.w & 0xffff0000u);
            }
            int e = e0;
            for (; e + 4 <= e1; e += 4) {
                int s0 = csr[e], s1 = csr[e + 1], s2 = csr[e + 2], s3 = csr[e + 3];
                uint4 v0 = tabh[s0];
                uint4 v1 = tabh[s1];
                uint4 v2 = tabh[s2];
                uint4 v3 = tabh[s3];
                acc8_bf16(acc, v0);
                acc8_bf16(acc, v1);
                acc8_bf16(acc, v2);
                acc8_bf16(acc, v3);
            }
            for (; e < e1; e++) {
                acc8_bf16(acc, tabh[csr[e]]);
            }
        }
        float d = dinv[node];
        float* ar = &aggs[node_l * STR + q * 8];
        #pragma unroll
        for (int j = 0; j < 8; j++) ar[j] = acc[j] * d;
    }
    __syncthreads();
    if (POOL) sarr[tid] = 0.f;
    if (valid) {
        const float* arow = &aggs[node_l * STR];
        float acc2[OPF];
        #pragma unroll
        for (int j = 0; j < OPF; j++) acc2[j] = 0.f;
        for (int k = 0; k < INF; k++) {
            float xk = arow[k];
            #pragma unroll
            for (int j = 0; j < OPF; j++) acc2[j] += xk * Ws[k * OUTF + q * OPF + j];
        }
        if (!POOL) {
            float scale = dinv[node];
            unsigned* lo_row = go_lo + (size_t)node * 16;
            unsigned* hi_row = go_hi + (size_t)node * 4;
            #pragma unroll
            for (int j = 0; j < OPF / 2; j++) {
                int f = q * OPF + 2 * j;
                float v0 = fmaxf(acc2[2 * j] + bias[f], 0.f) * scale;
                float v1 = fmaxf(acc2[2 * j + 1] + bias[f + 1], 0.f) * scale;
                unsigned u = pack2_bf16(v0, v1);
                int ui = q * (OPF / 2) + j;
                if (ui < 16) lo_row[ui] = u;
                else         hi_row[ui - 16] = u;
            }
        } else {
            float s = 0.f;
            #pragma unroll
            for (int j = 0; j < OPF; j++) {
                int f = q * OPF + j;
                s += fmaxf(acc2[j] + bias[f], 0.f) * lw[f];
            }
            sarr[tid] = s;
        }
    }
    if (POOL) {
        __syncthreads();
        if (tid < 64) {
            float s = 0.f;
            #pragma unroll
            for (int q2 = 0; q2 < TPN; q2++) s += sarr[tid * TPN + q2];
            int node2 = blockIdx.x * 64 + tid;
            bool v2 = (node2 < n);
            int g = batch[v2 ? node2 : (n - 1)];
            if (!v2) s = 0.f;
            int g0 = __shfl(g, 0, 64);
            if (__all(g == g0)) {
                #pragma unroll
                for (int off = 32; off > 0; off >>= 1) s += __shfl_xor(s, off, 64);
                if (tid == 0) atomicAdd(&g_sum[g0], s);
            } else {
                if (v2) atomicAdd(&g_sum[g], s);
            }
        }
    }
}

__global__ void finalize_kernel(const float* __restrict__ g_sum,
                                const int* __restrict__ batch,
                                const float* __restrict__ lin_b,
                                float* __restrict__ out, int n, int G) {
    int b = blockIdx.x * blockDim.x + threadIdx.x;
    if (b >= G) return;
    int lo = 0, hi = n;
    while (lo < hi) { int m = (lo + hi) >> 1; if (batch[m] < b) lo = m + 1; else hi = m; }
    int lo2 = lo, hi2 = n;
    while (lo2 < hi2) { int m = (lo2 + hi2) >> 1; if (batch[m] < b + 1) lo2 = m + 1; else hi2 = m; }
    int cnt = lo2 - lo;
    out[b] = g_sum[b] / (float)(cnt > 0 ? cnt : 1) + lin_b[0];
}

// ---------------- launch ----------------

static inline size_t align_up(size_t v, size_t a) { return (v + a - 1) / a * a; }

extern "C" void kernel_launch(void* const* d_in, const int* in_sizes, int n_in,
                              void* d_out, int out_size, void* d_ws, size_t ws_size,
                              hipStream_t stream) {
    const float* x      = (const float*)d_in[0];
    const int*   esrc   = (const int*)d_in[1];
    const int*   batch  = (const int*)d_in[2];
    const float* W1     = (const float*)d_in[3];
    const float* b1     = (const float*)d_in[4];
    const float* W2     = (const float*)d_in[5];
    const float* b2     = (const float*)d_in[6];
    const float* W3     = (const float*)d_in[7];
    const float* b3     = (const float*)d_in[8];
    const float* lin_w  = (const float*)d_in[9];
    const float* lin_b  = (const float*)d_in[10];
    float* out = (float*)d_out;

    const int n = in_sizes[0] / 30;
    const int E = in_sizes[1] / 2;
    const int G = out_size;
    const int* edst = esrc + E;

    char* w = (char*)d_ws;
    size_t off = 0;
    auto take = [&](size_t bytes) { size_t o = off; off = align_up(off + bytes, 256); return (void*)(w + o); };
    int*      bucket_cnt  = (int*)take((size_t)RBKT * 4);
    int*      bucket_base = (int*)take((size_t)(RBKT + 1) * 4);
    int*      rowptr      = (int*)take((size_t)(n + 1) * 4);
    float*    dinv        = (float*)take((size_t)n * 4);
    int*      csr         = (int*)take((size_t)E * 4);
    float*    g_sum       = (float*)take((size_t)G * 4);
    // bucket_data (9.6 MB) dead after buildB; alias with xs1 (6.4 MB)
    size_t bd = (size_t)RBKT * CAP * 4;
    size_t x1 = (size_t)n * 16 * 4;
    void* shared_region = take(bd > x1 ? bd : x1);
    int*      bucket_data = (int*)shared_region;
    unsigned* xs1         = (unsigned*)shared_region;         // layer-1 table (16 uints/row)
    unsigned* tbA_lo      = (unsigned*)take((size_t)n * 16 * 4);
    unsigned* tbA_hi      = (unsigned*)take((size_t)n * 4 * 4);
    unsigned* tbB_lo      = (unsigned*)take((size_t)n * 16 * 4);
    unsigned* tbB_hi      = (unsigned*)take((size_t)n * 4 * 4);
    (void)ws_size;

    clear_kernel<<<1, 256, 0, stream>>>(bucket_cnt, g_sum, G);

    binA_kernel<<<(E + EPB - 1) / EPB, 256, 0, stream>>>(esrc, edst, E, bucket_cnt, bucket_data);
    scan_buckets_kernel<<<1, 256, 0, stream>>>(bucket_cnt, bucket_base);
    buildB_kernel<<<RBKT, 256, 0, stream>>>(bucket_cnt, bucket_base, bucket_data,
                                            rowptr, csr, dinv, n);

    int nblk = (n + 63) / 64;

    // layer 1: single 64 B-row table (30 feats), TPN=4 -> split output
    scale_bf16_kernel<<<((size_t)n * 16 + 255) / 256, 256, 0, stream>>>(x, dinv, xs1, n);
    fused_layer_kernel<30, 4, false, false><<<nblk, 256, 0, stream>>>(
        xs1, nullptr, rowptr, csr, dinv, W1, b1, nullptr, nullptr,
        tbA_lo, tbA_hi, nullptr, n);
    // layer 2: split input (lo 64 B line-aligned + hi 16 B L2-resident), TPN=5
    fused_layer_kernel<HID, 5, true, false><<<nblk, 320, 0, stream>>>(
        tbA_lo, tbA_hi, rowptr, csr, dinv, W2, b2, nullptr, nullptr,
        tbB_lo, tbB_hi, nullptr, n);
    // layer 3: split input, fused pool + linear
    fused_layer_kernel<HID, 5, true, true><<<nblk, 320, 0, stream>>>(
        tbB_lo, tbB_hi, rowptr, csr, dinv, W3, b3, lin_w, batch,
        nullptr, nullptr, g_sum, n);

    finalize_kernel<<<1, 256, 0, stream>>>(g_sum, batch, lin_b, out, n, G);
}

// Round 12
// 256.243 us; speedup vs baseline: 1.5607x; 1.5607x over previous
//
#include <hip/hip_runtime.h>

#define HID 40
#define RBKT 196          // buckets of 512 nodes: covers n <= 100352
#define BSH 9             // bucket shift (512 nodes per bucket)
#define CAP 12288         // per-bucket edge capacity (mean 8192, +45 sigma)
#define EPB 4096          // edges per block in binning pass
#define NKEY 16384        // sort bins: 256 graphs x 64 degree classes

// ---------------- bf16 helpers ----------------

__device__ inline unsigned pack2_bf16(float a, float b) {
    unsigned ua = __float_as_uint(a);
    unsigned ub = __float_as_uint(b);
    ua = (ua + 0x7fffu + ((ua >> 16) & 1u)) >> 16;            // RNE, low half
    ub = (ub + 0x7fffu + ((ub >> 16) & 1u)) & 0xffff0000u;    // RNE, high half
    return ua | ub;
}

__device__ inline void acc8_bf16(float* acc, uint4 v) {
    acc[0] += __uint_as_float(v.x << 16);
    acc[1] += __uint_as_float(v.x & 0xffff0000u);
    acc[2] += __uint_as_float(v.y << 16);
    acc[3] += __uint_as_float(v.y & 0xffff0000u);
    acc[4] += __uint_as_float(v.z << 16);
    acc[5] += __uint_as_float(v.z & 0xffff0000u);
    acc[6] += __uint_as_float(v.w << 16);
    acc[7] += __uint_as_float(v.w & 0xffff0000u);
}

// zero bucket_cnt, g_sum, ghist (launch 64 blocks x 256)
__global__ void clear_kernel(int* __restrict__ bucket_cnt, float* __restrict__ g_sum,
                             int* __restrict__ ghist, int G) {
    int t = blockIdx.x * blockDim.x + threadIdx.x;
    if (t < RBKT) bucket_cnt[t] = 0;
    if (t < G) g_sum[t] = 0.f;
    if (t < NKEY) ghist[t] = 0;
}

// ---------------- CSR build (two-level bucketed) ----------------

__global__ __launch_bounds__(256) void binA_kernel(
        const int* __restrict__ esrc, const int* __restrict__ edst, int E,
        int* __restrict__ bucket_cnt, int* __restrict__ bucket_data) {
    __shared__ int cnt_l[RBKT];
    __shared__ int base_l[RBKT];
    int t = threadIdx.x;
    for (int b = t; b < RBKT; b += 256) cnt_l[b] = 0;
    __syncthreads();
    int e0 = blockIdx.x * EPB;
    int e1 = min(e0 + EPB, E);
    for (int e = e0 + t; e < e1; e += 256) {
        atomicAdd(&cnt_l[edst[e] >> BSH], 1);
    }
    __syncthreads();
    for (int b = t; b < RBKT; b += 256) {
        int c = cnt_l[b];
        base_l[b] = (c > 0) ? atomicAdd(&bucket_cnt[b], c) : 0;
        cnt_l[b] = 0;
    }
    __syncthreads();
    for (int e = e0 + t; e < e1; e += 256) {
        int d = edst[e];
        int s = esrc[e];
        int b = d >> BSH;
        int off = base_l[b] + atomicAdd(&cnt_l[b], 1);
        if (off < CAP) bucket_data[(size_t)b * CAP + off] = (s << BSH) | (d & 511);
    }
}

__global__ void scan_buckets_kernel(const int* __restrict__ cnt, int* __restrict__ base) {
    __shared__ int s[256];
    int t = threadIdx.x;
    int c = (t < RBKT) ? min(cnt[t], CAP) : 0;
    s[t] = c;
    __syncthreads();
    for (int off = 1; off < 256; off <<= 1) {
        int y = (t >= off) ? s[t - off] : 0;
        __syncthreads();
        s[t] += y;
        __syncthreads();
    }
    if (t < RBKT) base[t] = s[t] - c;
    if (t == RBKT - 1) base[RBKT] = s[t];
}

__global__ __launch_bounds__(256) void buildB_kernel(
        const int* __restrict__ bucket_cnt, const int* __restrict__ bucket_base,
        const int* __restrict__ bucket_data,
        int* __restrict__ rowptr, int* __restrict__ csr,
        float* __restrict__ dinv, int n) {
    __shared__ int deg_l[512];
    __shared__ int off_l[512];
    __shared__ int ps[256];
    int r = blockIdx.x;
    int t = threadIdx.x;
    int cnt = min(bucket_cnt[r], CAP);
    int base = bucket_base[r];
    int node0 = r << BSH;
    int nr = min(512, n - node0);
    for (int i = t; i < 512; i += 256) deg_l[i] = 0;
    __syncthreads();
    const int* data = bucket_data + (size_t)r * CAP;
    for (int e = t; e < cnt; e += 256) atomicAdd(&deg_l[data[e] & 511], 1);
    __syncthreads();
    int a0 = deg_l[2 * t], a1 = deg_l[2 * t + 1];
    ps[t] = a0 + a1;
    __syncthreads();
    for (int off = 1; off < 256; off <<= 1) {
        int y = (t >= off) ? ps[t - off] : 0;
        __syncthreads();
        ps[t] += y;
        __syncthreads();
    }
    int excl = ps[t] - (a0 + a1);
    off_l[2 * t] = excl;
    off_l[2 * t + 1] = excl + a0;
    __syncthreads();
    for (int i = t; i < nr; i += 256) {
        rowptr[node0 + i] = base + off_l[i];
        dinv[node0 + i] = rsqrtf((float)(deg_l[i] + 1));
    }
    if (r == RBKT - 1 && t == 0) rowptr[n] = base + cnt;
    __syncthreads();
    for (int e = t; e < cnt; e += 256) {
        int v = data[e];
        int p = atomicAdd(&off_l[v & 511], 1);
        csr[base + p] = v >> BSH;
    }
}

// ---------------- degree-balancing sort (counting sort by graph,degree) ----------------

__global__ void sort_hist_kernel(const int* __restrict__ rowptr, const int* __restrict__ batch,
                                 int* __restrict__ ghist, int n) {
    int i = blockIdx.x * blockDim.x + threadIdx.x;
    if (i >= n) return;
    int deg = min(rowptr[i + 1] - rowptr[i], 63);
    atomicAdd(&ghist[batch[i] * 64 + deg], 1);
}

// single-block exclusive scan of cnt[0..m) -> base[0..m] (1024 threads)
__global__ void scan_kernel(const int* __restrict__ cnt, int* __restrict__ base, int m) {
    __shared__ int ws[16];
    __shared__ int carry;
    int tid = threadIdx.x;
    int lane = tid & 63, wid = tid >> 6;
    if (tid == 0) carry = 0;
    __syncthreads();
    for (int b0 = 0; b0 < m; b0 += 1024) {
        int i = b0 + tid;
        int v = (i < m) ? cnt[i] : 0;
        int x = v;
        #pragma unroll
        for (int off = 1; off < 64; off <<= 1) {
            int y = __shfl_up(x, off, 64);
            if (lane >= off) x += y;
        }
        if (lane == 63) ws[wid] = x;
        __syncthreads();
        if (tid == 0) {
            int acc = carry;
            #pragma unroll
            for (int w2 = 0; w2 < 16; w2++) { int tt = ws[w2]; ws[w2] = acc; acc += tt; }
            carry = acc;
        }
        __syncthreads();
        if (i < m) base[i] = ws[wid] + (x - v);
        __syncthreads();
    }
    if (tid == 0) base[m] = carry;
}

__global__ void sort_scatter_kernel(const int* __restrict__ rowptr, const int* __restrict__ batch,
                                    int* __restrict__ gbase, int* __restrict__ perm, int n) {
    int i = blockIdx.x * blockDim.x + threadIdx.x;
    if (i >= n) return;
    int deg = min(rowptr[i + 1] - rowptr[i], 63);
    int key = batch[i] * 64 + deg;
    int pos = atomicAdd(&gbase[key], 1);
    perm[pos] = i;
}

// ---------------- layer kernels ----------------

// x (f32, n x 30) * dinv -> bf16 table, 16 uints/row (32 slots, last 2 zero)
__global__ __launch_bounds__(256) void scale_bf16_kernel(
        const float* __restrict__ x, const float* __restrict__ dinv,
        unsigned* __restrict__ xs, int n) {
    int t = blockIdx.x * blockDim.x + threadIdx.x;
    int i = t >> 4, p = t & 15;
    if (i >= n) return;
    float a = 0.f, b = 0.f;
    if (p < 15) {
        float d = dinv[i];
        a = x[i * 30 + 2 * p] * d;
        b = x[i * 30 + 2 * p + 1] * d;
    }
    xs[(size_t)i * 16 + p] = pack2_bf16(a, b);
}

// Fused gather + transform (+ optional pool) — exact round-7 structure
// (unroll 4, single table) + degree-balanced perm indirection.
// 64 nodes/block, TPN threads/node. Input rows = TPN uint4s of bf16.
template <int INF, int TPN, int OUTF, bool POOL>
__global__ __launch_bounds__(64 * TPN) void fused_layer_kernel(
        const unsigned* __restrict__ xs, const int* __restrict__ rowptr,
        const int* __restrict__ csr, const float* __restrict__ dinv,
        const int* __restrict__ perm,
        const float* __restrict__ W, const float* __restrict__ bias,
        const float* __restrict__ lin_w, const int* __restrict__ batch,
        unsigned* __restrict__ gout, float* __restrict__ g_sum, int n) {
    constexpr int NT  = 64 * TPN;       // block threads
    constexpr int STR = 8 * TPN + 1;    // agg LDS row stride (floats)
    constexpr int OPF = OUTF / TPN;     // outputs per thread
    __shared__ float Ws[INF * OUTF];
    __shared__ float aggs[64 * STR];
    __shared__ float lw[POOL ? OUTF : 1];
    __shared__ float sarr[POOL ? NT : 1];
    const int tid = threadIdx.x;
    for (int t = tid; t < INF * OUTF; t += NT) Ws[t] = W[t];
    if (POOL) {
        for (int t = tid; t < OUTF; t += NT) lw[t] = lin_w[t];
    }
    const int node_l = tid / TPN, q = tid - node_l * TPN;
    const int j = blockIdx.x * 64 + node_l;
    const bool valid = (j < n);
    const int node = perm[valid ? j : 0];
    if (valid) {
        const uint4* tab = reinterpret_cast<const uint4*>(xs);
        float acc[8];
        {
            uint4 v = tab[(size_t)node * TPN + q];     // self loop
            acc[0] = __uint_as_float(v.x << 16);
            acc[1] = __uint_as_float(v.x & 0xffff0000u);
            acc[2] = __uint_as_float(v.y << 16);
            acc[3] = __uint_as_float(v.y & 0xffff0000u);
            acc[4] = __uint_as_float(v.z << 16);
            acc[5] = __uint_as_float(v.z & 0xffff0000u);
            acc[6] = __uint_as_float(v.w << 16);
            acc[7] = __uint_as_float(v.w & 0xffff0000u);
        }
        int e0 = rowptr[node], e1 = rowptr[node + 1];
        int e = e0;
        for (; e + 4 <= e1; e += 4) {                  // 4-way unroll
            int s0 = csr[e], s1 = csr[e + 1], s2 = csr[e + 2], s3 = csr[e + 3];
            uint4 v0 = tab[(size_t)s0 * TPN + q];
            uint4 v1 = tab[(size_t)s1 * TPN + q];
            uint4 v2 = tab[(size_t)s2 * TPN + q];
            uint4 v3 = tab[(size_t)s3 * TPN + q];
            acc8_bf16(acc, v0);
            acc8_bf16(acc, v1);
            acc8_bf16(acc, v2);
            acc8_bf16(acc, v3);
        }
        for (; e < e1; e++) {
            acc8_bf16(acc, tab[(size_t)csr[e] * TPN + q]);
        }
        float d = dinv[node];
        float* ar = &aggs[node_l * STR + q * 8];
        #pragma unroll
        for (int jj = 0; jj < 8; jj++) ar[jj] = acc[jj] * d;
    }
    __syncthreads();
    if (POOL) sarr[tid] = 0.f;
    if (valid) {
        const float* arow = &aggs[node_l * STR];
        float acc2[OPF];
        #pragma unroll
        for (int jj = 0; jj < OPF; jj++) acc2[jj] = 0.f;
        for (int k = 0; k < INF; k++) {
            float xk = arow[k];
            #pragma unroll
            for (int jj = 0; jj < OPF; jj++) acc2[jj] += xk * Ws[k * OUTF + q * OPF + jj];
        }
        if (!POOL) {
            float scale = dinv[node];
            unsigned* orow = gout + (size_t)node * (OUTF / 2) + q * (OPF / 2);
            #pragma unroll
            for (int jj = 0; jj < OPF / 2; jj++) {
                int f = q * OPF + 2 * jj;
                float v0 = fmaxf(acc2[2 * jj] + bias[f], 0.f) * scale;
                float v1 = fmaxf(acc2[2 * jj + 1] + bias[f + 1], 0.f) * scale;
                orow[jj] = pack2_bf16(v0, v1);
            }
        } else {
            float s = 0.f;
            #pragma unroll
            for (int jj = 0; jj < OPF; jj++) {
                int f = q * OPF + jj;
                s += fmaxf(acc2[jj] + bias[f], 0.f) * lw[f];
            }
            sarr[tid] = s;
        }
    }
    if (POOL) {
        __syncthreads();
        if (tid < 64) {
            float s = 0.f;
            #pragma unroll
            for (int q2 = 0; q2 < TPN; q2++) s += sarr[tid * TPN + q2];
            int j2 = blockIdx.x * 64 + tid;
            bool v2 = (j2 < n);
            int node2 = perm[v2 ? j2 : 0];
            int g = batch[node2];
            if (!v2) { s = 0.f; g = batch[perm[n - 1]]; }
            int g0 = __shfl(g, 0, 64);
            if (__all(g == g0)) {
                #pragma unroll
                for (int off = 32; off > 0; off >>= 1) s += __shfl_xor(s, off, 64);
                if (tid == 0) atomicAdd(&g_sum[g0], s);
            } else {
                if (v2) atomicAdd(&g_sum[g], s);
            }
        }
    }
}

__global__ void finalize_kernel(const float* __restrict__ g_sum,
                                const int* __restrict__ batch,
                                const float* __restrict__ lin_b,
                                float* __restrict__ out, int n, int G) {
    int b = blockIdx.x * blockDim.x + threadIdx.x;
    if (b >= G) return;
    int lo = 0, hi = n;
    while (lo < hi) { int m = (lo + hi) >> 1; if (batch[m] < b) lo = m + 1; else hi = m; }
    int lo2 = lo, hi2 = n;
    while (lo2 < hi2) { int m = (lo2 + hi2) >> 1; if (batch[m] < b + 1) lo2 = m + 1; else hi2 = m; }
    int cnt = lo2 - lo;
    out[b] = g_sum[b] / (float)(cnt > 0 ? cnt : 1) + lin_b[0];
}

// ---------------- launch ----------------

static inline size_t align_up(size_t v, size_t a) { return (v + a - 1) / a * a; }

extern "C" void kernel_launch(void* const* d_in, const int* in_sizes, int n_in,
                              void* d_out, int out_size, void* d_ws, size_t ws_size,
                              hipStream_t stream) {
    const float* x      = (const float*)d_in[0];
    const int*   esrc   = (const int*)d_in[1];
    const int*   batch  = (const int*)d_in[2];
    const float* W1     = (const float*)d_in[3];
    const float* b1     = (const float*)d_in[4];
    const float* W2     = (const float*)d_in[5];
    const float* b2     = (const float*)d_in[6];
    const float* W3     = (const float*)d_in[7];
    const float* b3     = (const float*)d_in[8];
    const float* lin_w  = (const float*)d_in[9];
    const float* lin_b  = (const float*)d_in[10];
    float* out = (float*)d_out;

    const int n = in_sizes[0] / 30;
    const int E = in_sizes[1] / 2;
    const int G = out_size;
    const int* edst = esrc + E;

    char* w = (char*)d_ws;
    size_t off = 0;
    auto take = [&](size_t bytes) { size_t o = off; off = align_up(off + bytes, 256); return (void*)(w + o); };
    int*      bucket_cnt  = (int*)take((size_t)RBKT * 4);
    int*      bucket_base = (int*)take((size_t)(RBKT + 1) * 4);
    int*      rowptr      = (int*)take((size_t)(n + 1) * 4);
    float*    dinv        = (float*)take((size_t)n * 4);
    int*      csr         = (int*)take((size_t)E * 4);
    float*    g_sum       = (float*)take((size_t)G * 4);
    int*      ghist       = (int*)take((size_t)NKEY * 4);
    int*      gbase       = (int*)take((size_t)(NKEY + 1) * 4);
    int*      perm        = (int*)take((size_t)n * 4);
    // bucket_data (9.6 MB) dead after buildB; alias with xs1 (6.4 MB)
    size_t bd = (size_t)RBKT * CAP * 4;
    size_t x1 = (size_t)n * 16 * 4;
    void* shared_region = take(bd > x1 ? bd : x1);
    int*      bucket_data = (int*)shared_region;
    unsigned* xs1         = (unsigned*)shared_region;
    unsigned* tbA         = (unsigned*)take((size_t)n * 20 * 4);  // bf16 table (20 uints/row)
    unsigned* tbB         = (unsigned*)take((size_t)n * 20 * 4);
    (void)ws_size;

    clear_kernel<<<(NKEY + 255) / 256, 256, 0, stream>>>(bucket_cnt, g_sum, ghist, G);

    binA_kernel<<<(E + EPB - 1) / EPB, 256, 0, stream>>>(esrc, edst, E, bucket_cnt, bucket_data);
    scan_buckets_kernel<<<1, 256, 0, stream>>>(bucket_cnt, bucket_base);
    buildB_kernel<<<RBKT, 256, 0, stream>>>(bucket_cnt, bucket_base, bucket_data,
                                            rowptr, csr, dinv, n);

    // degree-balancing permutation (counting sort by graph,degree)
    sort_hist_kernel<<<(n + 255) / 256, 256, 0, stream>>>(rowptr, batch, ghist, n);
    scan_kernel<<<1, 1024, 0, stream>>>(ghist, gbase, NKEY);
    sort_scatter_kernel<<<(n + 255) / 256, 256, 0, stream>>>(rowptr, batch, gbase, perm, n);

    int nblk = (n + 63) / 64;

    // layer 1: 4 threads/node (16-uint rows), fused gather+transform 30->40
    scale_bf16_kernel<<<((size_t)n * 16 + 255) / 256, 256, 0, stream>>>(x, dinv, xs1, n);
    fused_layer_kernel<30, 4, HID, false><<<nblk, 256, 0, stream>>>(
        xs1, rowptr, csr, dinv, perm, W1, b1, nullptr, nullptr, tbA, nullptr, n);
    // layer 2: 5 threads/node (20-uint rows), fused gather+transform 40->40
    fused_layer_kernel<HID, 5, HID, false><<<nblk, 320, 0, stream>>>(
        tbA, rowptr, csr, dinv, perm, W2, b2, nullptr, nullptr, tbB, nullptr, n);
    // layer 3: fused gather+transform+pool+linear
    fused_layer_kernel<HID, 5, HID, true><<<nblk, 320, 0, stream>>>(
        tbB, rowptr, csr, dinv, perm, W3, b3, lin_w, batch, nullptr, g_sum, n);

    finalize_kernel<<<1, 256, 0, stream>>>(g_sum, batch, lin_b, out, n, G);
}

// Round 13
// 209.557 us; speedup vs baseline: 1.9084x; 1.2228x over previous
//
#include <hip/hip_runtime.h>

#define HID 40
#define RBKT 196          // buckets of 512 nodes: covers n <= 100352
#define BSH 9             // bucket shift (512 nodes per bucket)
#define CAP 12288         // per-bucket edge capacity (mean 8192, +45 sigma)
#define EPB 4096          // edges per block in binning pass

// ---------------- bf16 helpers ----------------

__device__ inline unsigned pack2_bf16(float a, float b) {
    unsigned ua = __float_as_uint(a);
    unsigned ub = __float_as_uint(b);
    ua = (ua + 0x7fffu + ((ua >> 16) & 1u)) >> 16;            // RNE, low half
    ub = (ub + 0x7fffu + ((ub >> 16) & 1u)) & 0xffff0000u;    // RNE, high half
    return ua | ub;
}

__device__ inline void acc8_bf16(float* acc, uint4 v) {
    acc[0] += __uint_as_float(v.x << 16);
    acc[1] += __uint_as_float(v.x & 0xffff0000u);
    acc[2] += __uint_as_float(v.y << 16);
    acc[3] += __uint_as_float(v.y & 0xffff0000u);
    acc[4] += __uint_as_float(v.z << 16);
    acc[5] += __uint_as_float(v.z & 0xffff0000u);
    acc[6] += __uint_as_float(v.w << 16);
    acc[7] += __uint_as_float(v.w & 0xffff0000u);
}

__global__ void clear_kernel(int* __restrict__ bucket_cnt, float* __restrict__ g_sum, int G) {
    int t = blockIdx.x * blockDim.x + threadIdx.x;
    if (t < RBKT) bucket_cnt[t] = 0;
    if (t < G) g_sum[t] = 0.f;
}

// ---------------- CSR build (two-level bucketed, rows split by src half) ----------------

__global__ __launch_bounds__(256) void binA_kernel(
        const int* __restrict__ esrc, const int* __restrict__ edst, int E,
        int* __restrict__ bucket_cnt, int* __restrict__ bucket_data) {
    __shared__ int cnt_l[RBKT];
    __shared__ int base_l[RBKT];
    int t = threadIdx.x;
    for (int b = t; b < RBKT; b += 256) cnt_l[b] = 0;
    __syncthreads();
    int e0 = blockIdx.x * EPB;
    int e1 = min(e0 + EPB, E);
    for (int e = e0 + t; e < e1; e += 256) {
        atomicAdd(&cnt_l[edst[e] >> BSH], 1);
    }
    __syncthreads();
    for (int b = t; b < RBKT; b += 256) {
        int c = cnt_l[b];
        base_l[b] = (c > 0) ? atomicAdd(&bucket_cnt[b], c) : 0;
        cnt_l[b] = 0;
    }
    __syncthreads();
    for (int e = e0 + t; e < e1; e += 256) {
        int d = edst[e];
        int s = esrc[e];
        int b = d >> BSH;
        int off = base_l[b] + atomicAdd(&cnt_l[b], 1);
        if (off < CAP) bucket_data[(size_t)b * CAP + off] = (s << BSH) | (d & 511);
    }
}

__global__ void scan_buckets_kernel(const int* __restrict__ cnt, int* __restrict__ base) {
    __shared__ int s[256];
    int t = threadIdx.x;
    int c = (t < RBKT) ? min(cnt[t], CAP) : 0;
    s[t] = c;
    __syncthreads();
    for (int off = 1; off < 256; off <<= 1) {
        int y = (t >= off) ? s[t - off] : 0;
        __syncthreads();
        s[t] += y;
        __syncthreads();
    }
    if (t < RBKT) base[t] = s[t] - c;
    if (t == RBKT - 1) base[RBKT] = s[t];
}

// builds rowptr/csr/dinv + mid: each row stores srcs < half first, then >= half
__global__ __launch_bounds__(256) void buildB_kernel(
        const int* __restrict__ bucket_cnt, const int* __restrict__ bucket_base,
        const int* __restrict__ bucket_data,
        int* __restrict__ rowptr, int* __restrict__ mid, int* __restrict__ csr,
        float* __restrict__ dinv, int n, int half) {
    __shared__ int deg_l[512];
    __shared__ int deg_lo[512];
    __shared__ int off_lo[512];
    __shared__ int off_hi[512];
    __shared__ int ps[256];
    int r = blockIdx.x;
    int t = threadIdx.x;
    int cnt = min(bucket_cnt[r], CAP);
    int base = bucket_base[r];
    int node0 = r << BSH;
    int nr = min(512, n - node0);
    for (int i = t; i < 512; i += 256) { deg_l[i] = 0; deg_lo[i] = 0; }
    __syncthreads();
    const int* data = bucket_data + (size_t)r * CAP;
    for (int e = t; e < cnt; e += 256) {
        int v = data[e];
        atomicAdd(&deg_l[v & 511], 1);
        if ((v >> BSH) < half) atomicAdd(&deg_lo[v & 511], 1);
    }
    __syncthreads();
    int a0 = deg_l[2 * t], a1 = deg_l[2 * t + 1];
    ps[t] = a0 + a1;
    __syncthreads();
    for (int off = 1; off < 256; off <<= 1) {
        int y = (t >= off) ? ps[t - off] : 0;
        __syncthreads();
        ps[t] += y;
        __syncthreads();
    }
    int excl = ps[t] - (a0 + a1);
    off_lo[2 * t] = excl;
    off_lo[2 * t + 1] = excl + a0;
    off_hi[2 * t] = excl + deg_lo[2 * t];
    off_hi[2 * t + 1] = excl + a0 + deg_lo[2 * t + 1];
    __syncthreads();
    for (int i = t; i < nr; i += 256) {
        int rp = base + off_lo[i];
        rowptr[node0 + i] = rp;
        mid[node0 + i] = rp + deg_lo[i];
        dinv[node0 + i] = rsqrtf((float)(deg_l[i] + 1));
    }
    if (r == RBKT - 1 && t == 0) rowptr[n] = base + cnt;
    __syncthreads();
    for (int e = t; e < cnt; e += 256) {
        int v = data[e];
        int s = v >> BSH;
        int d = v & 511;
        int p = (s < half) ? atomicAdd(&off_lo[d], 1) : atomicAdd(&off_hi[d], 1);
        csr[base + p] = s;
    }
}

// ---------------- layer kernels ----------------

// x (f32, n x 30) * dinv -> bf16 table, 16 uints/row (32 slots, last 2 zero)
__global__ __launch_bounds__(256) void scale_bf16_kernel(
        const float* __restrict__ x, const float* __restrict__ dinv,
        unsigned* __restrict__ xs, int n) {
    int t = blockIdx.x * blockDim.x + threadIdx.x;
    int i = t >> 4, p = t & 15;
    if (i >= n) return;
    float a = 0.f, b = 0.f;
    if (p < 15) {
        float d = dinv[i];
        a = x[i * 30 + 2 * p] * d;
        b = x[i * 30 + 2 * p + 1] * d;
    }
    xs[(size_t)i * 16 + p] = pack2_bf16(a, b);
}

// Fused gather + transform (+ optional pool) — exact round-7 structure
// (unroll 4, single table), edge loop split at mid[] so the live gather
// working set is a half-table (fits per-XCD L2).
template <int INF, int TPN, int OUTF, bool POOL>
__global__ __launch_bounds__(64 * TPN) void fused_layer_kernel(
        const unsigned* __restrict__ xs, const int* __restrict__ rowptr,
        const int* __restrict__ mid, const int* __restrict__ csr,
        const float* __restrict__ dinv,
        const float* __restrict__ W, const float* __restrict__ bias,
        const float* __restrict__ lin_w, const int* __restrict__ batch,
        unsigned* __restrict__ gout, float* __restrict__ g_sum, int n) {
    constexpr int NT  = 64 * TPN;       // block threads
    constexpr int STR = 8 * TPN + 1;    // agg LDS row stride (floats)
    constexpr int OPF = OUTF / TPN;     // outputs per thread
    __shared__ float Ws[INF * OUTF];
    __shared__ float aggs[64 * STR];
    __shared__ float lw[POOL ? OUTF : 1];
    __shared__ float sarr[POOL ? NT : 1];
    const int tid = threadIdx.x;
    for (int t = tid; t < INF * OUTF; t += NT) Ws[t] = W[t];
    if (POOL) {
        for (int t = tid; t < OUTF; t += NT) lw[t] = lin_w[t];
    }
    const int node_l = tid / TPN, q = tid - node_l * TPN;
    const int node = blockIdx.x * 64 + node_l;
    const bool valid = (node < n);
    if (valid) {
        const uint4* tab = reinterpret_cast<const uint4*>(xs);
        float acc[8];
        {
            uint4 v = tab[(size_t)node * TPN + q];     // self loop
            acc[0] = __uint_as_float(v.x << 16);
            acc[1] = __uint_as_float(v.x & 0xffff0000u);
            acc[2] = __uint_as_float(v.y << 16);
            acc[3] = __uint_as_float(v.y & 0xffff0000u);
            acc[4] = __uint_as_float(v.z << 16);
            acc[5] = __uint_as_float(v.z & 0xffff0000u);
            acc[6] = __uint_as_float(v.w << 16);
            acc[7] = __uint_as_float(v.w & 0xffff0000u);
        }
        int e0 = rowptr[node], m = mid[node], e1 = rowptr[node + 1];
        // phase A: srcs < n/2 (lower half-table, L2-resident)
        int e = e0;
        for (; e + 4 <= m; e += 4) {
            int s0 = csr[e], s1 = csr[e + 1], s2 = csr[e + 2], s3 = csr[e + 3];
            uint4 v0 = tab[(size_t)s0 * TPN + q];
            uint4 v1 = tab[(size_t)s1 * TPN + q];
            uint4 v2 = tab[(size_t)s2 * TPN + q];
            uint4 v3 = tab[(size_t)s3 * TPN + q];
            acc8_bf16(acc, v0);
            acc8_bf16(acc, v1);
            acc8_bf16(acc, v2);
            acc8_bf16(acc, v3);
        }
        for (; e < m; e++) {
            acc8_bf16(acc, tab[(size_t)csr[e] * TPN + q]);
        }
        // phase B: srcs >= n/2 (upper half-table)
        for (; e + 4 <= e1; e += 4) {
            int s0 = csr[e], s1 = csr[e + 1], s2 = csr[e + 2], s3 = csr[e + 3];
            uint4 v0 = tab[(size_t)s0 * TPN + q];
            uint4 v1 = tab[(size_t)s1 * TPN + q];
            uint4 v2 = tab[(size_t)s2 * TPN + q];
            uint4 v3 = tab[(size_t)s3 * TPN + q];
            acc8_bf16(acc, v0);
            acc8_bf16(acc, v1);
            acc8_bf16(acc, v2);
            acc8_bf16(acc, v3);
        }
        for (; e < e1; e++) {
            acc8_bf16(acc, tab[(size_t)csr[e] * TPN + q]);
        }
        float d = dinv[node];
        float* ar = &aggs[node_l * STR + q * 8];
        #pragma unroll
        for (int j = 0; j < 8; j++) ar[j] = acc[j] * d;
    }
    __syncthreads();
    if (POOL) sarr[tid] = 0.f;
    if (valid) {
        const float* arow = &aggs[node_l * STR];
        float acc2[OPF];
        #pragma unroll
        for (int j = 0; j < OPF; j++) acc2[j] = 0.f;
        for (int k = 0; k < INF; k++) {
            float xk = arow[k];
            #pragma unroll
            for (int j = 0; j < OPF; j++) acc2[j] += xk * Ws[k * OUTF + q * OPF + j];
        }
        if (!POOL) {
            float scale = dinv[node];
            unsigned* orow = gout + (size_t)node * (OUTF / 2) + q * (OPF / 2);
            #pragma unroll
            for (int j = 0; j < OPF / 2; j++) {
                int f = q * OPF + 2 * j;
                float v0 = fmaxf(acc2[2 * j] + bias[f], 0.f) * scale;
                float v1 = fmaxf(acc2[2 * j + 1] + bias[f + 1], 0.f) * scale;
                orow[j] = pack2_bf16(v0, v1);
            }
        } else {
            float s = 0.f;
            #pragma unroll
            for (int j = 0; j < OPF; j++) {
                int f = q * OPF + j;
                s += fmaxf(acc2[j] + bias[f], 0.f) * lw[f];
            }
            sarr[tid] = s;
        }
    }
    if (POOL) {
        __syncthreads();
        if (tid < 64) {
            float s = 0.f;
            #pragma unroll
            for (int q2 = 0; q2 < TPN; q2++) s += sarr[tid * TPN + q2];
            int node2 = blockIdx.x * 64 + tid;
            bool v2 = (node2 < n);
            int g = batch[v2 ? node2 : (n - 1)];
            if (!v2) s = 0.f;
            int g0 = __shfl(g, 0, 64);
            if (__all(g == g0)) {
                #pragma unroll
                for (int off = 32; off > 0; off >>= 1) s += __shfl_xor(s, off, 64);
                if (tid == 0) atomicAdd(&g_sum[g0], s);
            } else {
                if (v2) atomicAdd(&g_sum[g], s);
            }
        }
    }
}

__global__ void finalize_kernel(const float* __restrict__ g_sum,
                                const int* __restrict__ batch,
                                const float* __restrict__ lin_b,
                                float* __restrict__ out, int n, int G) {
    int b = blockIdx.x * blockDim.x + threadIdx.x;
    if (b >= G) return;
    int lo = 0, hi = n;
    while (lo < hi) { int m = (lo + hi) >> 1; if (batch[m] < b) lo = m + 1; else hi = m; }
    int lo2 = lo, hi2 = n;
    while (lo2 < hi2) { int m = (lo2 + hi2) >> 1; if (batch[m] < b + 1) lo2 = m + 1; else hi2 = m; }
    int cnt = lo2 - lo;
    out[b] = g_sum[b] / (float)(cnt > 0 ? cnt : 1) + lin_b[0];
}

// ---------------- launch ----------------

static inline size_t align_up(size_t v, size_t a) { return (v + a - 1) / a * a; }

extern "C" void kernel_launch(void* const* d_in, const int* in_sizes, int n_in,
                              void* d_out, int out_size, void* d_ws, size_t ws_size,
                              hipStream_t stream) {
    const float* x      = (const float*)d_in[0];
    const int*   esrc   = (const int*)d_in[1];
    const int*   batch  = (const int*)d_in[2];
    const float* W1     = (const float*)d_in[3];
    const float* b1     = (const float*)d_in[4];
    const float* W2     = (const float*)d_in[5];
    const float* b2     = (const float*)d_in[6];
    const float* W3     = (const float*)d_in[7];
    const float* b3     = (const float*)d_in[8];
    const float* lin_w  = (const float*)d_in[9];
    const float* lin_b  = (const float*)d_in[10];
    float* out = (float*)d_out;

    const int n = in_sizes[0] / 30;
    const int E = in_sizes[1] / 2;
    const int G = out_size;
    const int* edst = esrc + E;

    char* w = (char*)d_ws;
    size_t off = 0;
    auto take = [&](size_t bytes) { size_t o = off; off = align_up(off + bytes, 256); return (void*)(w + o); };
    int*      bucket_cnt  = (int*)take((size_t)RBKT * 4);
    int*      bucket_base = (int*)take((size_t)(RBKT + 1) * 4);
    int*      rowptr      = (int*)take((size_t)(n + 1) * 4);
    int*      mid         = (int*)take((size_t)n * 4);
    float*    dinv        = (float*)take((size_t)n * 4);
    int*      csr         = (int*)take((size_t)E * 4);
    float*    g_sum       = (float*)take((size_t)G * 4);
    // bucket_data (9.6 MB) dead after buildB; alias with xs1 (6.4 MB)
    size_t bd = (size_t)RBKT * CAP * 4;
    size_t x1 = (size_t)n * 16 * 4;
    void* shared_region = take(bd > x1 ? bd : x1);
    int*      bucket_data = (int*)shared_region;
    unsigned* xs1         = (unsigned*)shared_region;
    unsigned* tbA         = (unsigned*)take((size_t)n * 20 * 4);  // bf16 table (20 uints/row)
    unsigned* tbB         = (unsigned*)take((size_t)n * 20 * 4);
    (void)ws_size;

    clear_kernel<<<1, 256, 0, stream>>>(bucket_cnt, g_sum, G);

    binA_kernel<<<(E + EPB - 1) / EPB, 256, 0, stream>>>(esrc, edst, E, bucket_cnt, bucket_data);
    scan_buckets_kernel<<<1, 256, 0, stream>>>(bucket_cnt, bucket_base);
    buildB_kernel<<<RBKT, 256, 0, stream>>>(bucket_cnt, bucket_base, bucket_data,
                                            rowptr, mid, csr, dinv, n, n / 2);

    int nblk = (n + 63) / 64;

    // layer 1: 4 threads/node (16-uint rows), fused gather+transform 30->40
    scale_bf16_kernel<<<((size_t)n * 16 + 255) / 256, 256, 0, stream>>>(x, dinv, xs1, n);
    fused_layer_kernel<30, 4, HID, false><<<nblk, 256, 0, stream>>>(
        xs1, rowptr, mid, csr, dinv, W1, b1, nullptr, nullptr, tbA, nullptr, n);
    // layer 2: 5 threads/node (20-uint rows), fused gather+transform 40->40
    fused_layer_kernel<HID, 5, HID, false><<<nblk, 320, 0, stream>>>(
        tbA, rowptr, mid, csr, dinv, W2, b2, nullptr, nullptr, tbB, nullptr, n);
    // layer 3: fused gather+transform+pool+linear
    fused_layer_kernel<HID, 5, HID, true><<<nblk, 320, 0, stream>>>(
        tbB, rowptr, mid, csr, dinv, W3, b3, lin_w, batch, nullptr, g_sum, n);

    finalize_kernel<<<1, 256, 0, stream>>>(g_sum, batch, lin_b, out, n, G);
}